// Round 1
// baseline (1097.519 us; speedup 1.0000x reference)
//
#include <hip/hip_runtime.h>

typedef _Float16 half8 __attribute__((ext_vector_type(8)));
typedef float f32x16 __attribute__((ext_vector_type(16)));
typedef float f32x4v __attribute__((ext_vector_type(4)));

constexpr int S  = 2048;   // sequence length
constexpr int D  = 128;    // hidden dim
constexpr int TQ = 32;     // q rows per block
constexpr int NW = 8;      // waves per block (512 threads)
constexpr int CPW = S / NW;   // 256 score columns per wave
constexpr int NT  = CPW / 32; // 8 MFMA column tiles per wave
constexpr float SCALE = 0.08838834764831845f; // 1/sqrt(128)

// C/D layout (measured, m74/m101): col = lane&31, row = (reg&3) + 8*(reg>>2) + 4*(lane>>5)
__launch_bounds__(512, 2)
__global__ void attn_fwd(const float* __restrict__ Q,
                         const float* __restrict__ K,
                         const float* __restrict__ V,
                         float* __restrict__ Oc,
                         float* __restrict__ Oa) {
    const int b    = blockIdx.y;
    const int q0   = blockIdx.x * TQ;
    const int tid  = threadIdx.x;
    const int wave = tid >> 6;
    const int lane = tid & 63;
    const int l31  = lane & 31;
    const int hl   = lane >> 5;   // 0/1

    // P chunk buffer: 32 rows x 256 cols fp16, pad 8 halves -> row stride 528B
    // (16B-aligned for ds_read_b128; 132 dwords = 4 mod 32 -> mild 4-way aliasing)
    __shared__ _Float16 Pch[TQ][CPW + 8];
    __shared__ float red[NW][TQ];
    __shared__ float gmax[TQ];
    __shared__ float grs[TQ];               // reciprocal row sums
    __shared__ float cpart[4][TQ][32];      // k-half-1 context partials

    // ---- Q fragments: A[m=l31][k=hl*8+j + 16*s], held for whole QK^T ----
    const float* qrow = Q + ((size_t)b * S + (q0 + l31)) * D;
    half8 qf[8];
#pragma unroll
    for (int s = 0; s < 8; ++s) {
        const int d0 = s * 16 + hl * 8;
        f32x4v a = *(const f32x4v*)(qrow + d0);
        f32x4v c = *(const f32x4v*)(qrow + d0 + 4);
        qf[s][0] = (_Float16)a[0]; qf[s][1] = (_Float16)a[1];
        qf[s][2] = (_Float16)a[2]; qf[s][3] = (_Float16)a[3];
        qf[s][4] = (_Float16)c[0]; qf[s][5] = (_Float16)c[1];
        qf[s][6] = (_Float16)c[2]; qf[s][7] = (_Float16)c[3];
    }

    // ---- QK^T: wave owns columns [wave*256, wave*256+256) ----
    const float* kbase = K + (size_t)b * S * D;
    f32x16 acc[NT];
#pragma unroll
    for (int t = 0; t < NT; ++t) {
        f32x16 a;
#pragma unroll
        for (int r = 0; r < 16; ++r) a[r] = 0.0f;
        const float* krow = kbase + (size_t)(wave * CPW + t * 32 + l31) * D;
#pragma unroll
        for (int s = 0; s < 8; ++s) {
            const int d0 = s * 16 + hl * 8;
            f32x4v x = *(const f32x4v*)(krow + d0);
            f32x4v y = *(const f32x4v*)(krow + d0 + 4);
            half8 kf;
            kf[0] = (_Float16)x[0]; kf[1] = (_Float16)x[1];
            kf[2] = (_Float16)x[2]; kf[3] = (_Float16)x[3];
            kf[4] = (_Float16)y[0]; kf[5] = (_Float16)y[1];
            kf[6] = (_Float16)y[2]; kf[7] = (_Float16)y[3];
            a = __builtin_amdgcn_mfma_f32_32x32x16_f16(qf[s], kf, a, 0, 0, 0);
        }
        acc[t] = a;
    }

    // ---- scale + per-wave row max (butterfly within each 32-lane half) ----
    float mx[16];
#pragma unroll
    for (int r = 0; r < 16; ++r) {
        float m = -1e30f;
#pragma unroll
        for (int t = 0; t < NT; ++t) {
            acc[t][r] *= SCALE;
            m = fmaxf(m, acc[t][r]);
        }
#pragma unroll
        for (int off = 1; off < 32; off <<= 1)
            m = fmaxf(m, __shfl_xor(m, off, 64));
        mx[r] = m;
    }
    if (l31 < 16)
        red[wave][(l31 & 3) + 8 * (l31 >> 2) + 4 * hl] = mx[l31];
    __syncthreads();
    if (tid < TQ) {
        float m = red[0][tid];
#pragma unroll
        for (int w = 1; w < NW; ++w) m = fmaxf(m, red[w][tid]);
        gmax[tid] = m;
    }
    __syncthreads();

    // ---- exp + per-wave row sum ----
    float sm[16];
#pragma unroll
    for (int r = 0; r < 16; ++r) {
        const int row = (r & 3) + 8 * (r >> 2) + 4 * hl;
        const float g = gmax[row];
        float s = 0.0f;
#pragma unroll
        for (int t = 0; t < NT; ++t) {
            float p = __expf(acc[t][r] - g);
            acc[t][r] = p;
            s += p;
        }
#pragma unroll
        for (int off = 1; off < 32; off <<= 1)
            s += __shfl_xor(s, off, 64);
        sm[r] = s;
    }
    if (l31 < 16)
        red[wave][(l31 & 3) + 8 * (l31 >> 2) + 4 * hl] = sm[l31];
    __syncthreads();
    if (tid < TQ) {
        float s = 0.0f;
#pragma unroll
        for (int w = 0; w < NW; ++w) s += red[w][tid];
        grs[tid] = 1.0f / s;
    }
    __syncthreads();

    // ---- normalize + write attention probs (the big 536MB write) ----
    float* arow_base = Oa + ((size_t)b * S + q0) * S + wave * CPW;
#pragma unroll
    for (int r = 0; r < 16; ++r) {
        const int row = (r & 3) + 8 * (r >> 2) + 4 * hl;
        const float rv = grs[row];
        float* ar = arow_base + (size_t)row * S;
#pragma unroll
        for (int t = 0; t < NT; ++t) {
            float pn = acc[t][r] * rv;
            acc[t][r] = pn;
            ar[t * 32 + l31] = pn;
        }
    }

    // ---- P·V via LDS chunk transpose; wave w: d-tile = w&3, k-half = w>>2 ----
    const float* vbase = V + (size_t)b * S * D;
    const int dtile = wave & 3;
    const int khalf = wave >> 2;
    const int dcol  = dtile * 32 + l31;
    f32x16 ctx;
#pragma unroll
    for (int r = 0; r < 16; ++r) ctx[r] = 0.0f;

    for (int cw = 0; cw < NW; ++cw) {
        __syncthreads();
        if (wave == cw) {
#pragma unroll
            for (int r = 0; r < 16; ++r) {
                const int row = (r & 3) + 8 * (r >> 2) + 4 * hl;
#pragma unroll
                for (int t = 0; t < NT; ++t)
                    Pch[row][t * 32 + l31] = (_Float16)acc[t][r];
            }
        }
        __syncthreads();
#pragma unroll
        for (int s = 0; s < 8; ++s) {
            const int kk = khalf * 128 + s * 16 + hl * 8;
            half8 pf = *(const half8*)(&Pch[l31][kk]);   // A[m=l31][k..k+7]
            half8 vf;
#pragma unroll
            for (int j = 0; j < 8; ++j)
                vf[j] = (_Float16)vbase[(size_t)(cw * CPW + kk + j) * D + dcol];
            ctx = __builtin_amdgcn_mfma_f32_32x32x16_f16(pf, vf, ctx, 0, 0, 0);
        }
    }

    // ---- 2-way k-half reduction, write context ----
    __syncthreads();
    if (khalf == 1) {
#pragma unroll
        for (int r = 0; r < 16; ++r) {
            const int row = (r & 3) + 8 * (r >> 2) + 4 * hl;
            cpart[dtile][row][l31] = ctx[r];
        }
    }
    __syncthreads();
    if (khalf == 0) {
#pragma unroll
        for (int r = 0; r < 16; ++r) {
            const int row = (r & 3) + 8 * (r >> 2) + 4 * hl;
            float vsum = ctx[r] + cpart[dtile][row][l31];
            Oc[((size_t)b * S + q0 + row) * D + dcol] = vsum;
        }
    }
}

extern "C" void kernel_launch(void* const* d_in, const int* in_sizes, int n_in,
                              void* d_out, int out_size, void* d_ws, size_t ws_size,
                              hipStream_t stream) {
    const float* q = (const float*)d_in[0];
    const float* k = (const float*)d_in[1];
    const float* v = (const float*)d_in[2];
    const int B = in_sizes[0] / (S * D);   // 32
    float* ctx  = (float*)d_out;
    float* attn = ctx + (size_t)B * S * D;
    dim3 grid(S / TQ, B);
    attn_fwd<<<grid, dim3(512), 0, stream>>>(q, k, v, ctx, attn);
}